// Round 1
// baseline (266.271 us; speedup 1.0000x reference)
//
#include <hip/hip_runtime.h>
#include <math.h>

#define N_NODES 50000
#define K_NEI   32
#define D_FEAT  128
#define LEAKY   0.01f

// One node per 32-lane half-wave: lane owns float4 columns [4*lane, 4*lane+4).
// Single gather pass with no-max online softmax accumulation (scores bounded,
// exp() safe in f32). 256 threads/block = 8 nodes/block.
__global__ __launch_bounds__(256, 4) void feat_encoder_kernel(
    const float* __restrict__ feat,
    const int*   __restrict__ nei,
    const float* __restrict__ att,
    float*       __restrict__ out)
{
    const int lane = threadIdx.x & 31;
    const int node = blockIdx.x * 8 + (threadIdx.x >> 5);
    if (node >= N_NODES) return;

    const float4 a_ref = *(const float4*)&att[4 * lane];
    const float4 a_nei = *(const float4*)&att[D_FEAT + 4 * lane];

    // score_ref = feat[node] . a_ref  (reduced across the 32-lane group)
    const float4 f = *(const float4*)&feat[(size_t)node * D_FEAT + 4 * lane];
    float sref = f.x * a_ref.x + f.y * a_ref.y + f.z * a_ref.z + f.w * a_ref.w;
    #pragma unroll
    for (int off = 16; off >= 1; off >>= 1)
        sref += __shfl_xor(sref, off, 32);

    // each lane preloads one neighbor index; broadcast per-k via shfl
    const int idx = nei[node * K_NEI + lane];

    float  s = 0.f;
    float4 o = {0.f, 0.f, 0.f, 0.f};

    #pragma unroll
    for (int k = 0; k < K_NEI; ++k) {
        const int nk = __shfl(idx, k, 32);
        const float4 v = *(const float4*)&feat[(size_t)nk * D_FEAT + 4 * lane];

        float partial = v.x * a_nei.x + v.y * a_nei.y + v.z * a_nei.z + v.w * a_nei.w;
        #pragma unroll
        for (int off = 16; off >= 1; off >>= 1)
            partial += __shfl_xor(partial, off, 32);

        float score = partial + sref;
        score = (score >= 0.f) ? score : LEAKY * score;

        const float p = __expf(score);   // no-max softmax: |score| <~ 15, safe
        s += p;
        o.x += p * v.x;
        o.y += p * v.y;
        o.z += p * v.z;
        o.w += p * v.w;
    }

    const float inv = 1.0f / s;
    float4 r;
    r.x = o.x * inv; r.y = o.y * inv; r.z = o.z * inv; r.w = o.w * inv;
    // ELU (alpha=1)
    r.x = (r.x > 0.f) ? r.x : expm1f(r.x);
    r.y = (r.y > 0.f) ? r.y : expm1f(r.y);
    r.z = (r.z > 0.f) ? r.z : expm1f(r.z);
    r.w = (r.w > 0.f) ? r.w : expm1f(r.w);

    *(float4*)&out[(size_t)node * D_FEAT + 4 * lane] = r;
}

extern "C" void kernel_launch(void* const* d_in, const int* in_sizes, int n_in,
                              void* d_out, int out_size, void* d_ws, size_t ws_size,
                              hipStream_t stream) {
    const float* feat = (const float*)d_in[0];
    const int*   nei  = (const int*)d_in[1];
    const float* att  = (const float*)d_in[2];
    float*       out  = (float*)d_out;

    const int nodes_per_block = 8;
    dim3 grid((N_NODES + nodes_per_block - 1) / nodes_per_block);
    feat_encoder_kernel<<<grid, 256, 0, stream>>>(feat, nei, att, out);
}

// Round 2
// 221.539 us; speedup vs baseline: 1.2019x; 1.2019x over previous
//
#include <hip/hip_runtime.h>
#include <hip/hip_bf16.h>
#include <math.h>

#define N_NODES 50000
#define K_NEI   32
#define D_FEAT  128
#define LEAKY   0.01f

__device__ __forceinline__ float bf2f(unsigned short u) {
    return __uint_as_float(((unsigned int)u) << 16);
}
__device__ __forceinline__ unsigned short f2bf(float x) {
    __hip_bfloat16 b = __float2bfloat16(x);   // round-to-nearest-even
    union { __hip_bfloat16 b; unsigned short u; } c; c.b = b;
    return c.u;
}

// ---------- Phase 1: g = feat.a_nei, h = feat.a_ref, fb = bf16(feat) ----------
__global__ __launch_bounds__(256) void precompute_kernel(
    const float* __restrict__ feat,
    const float* __restrict__ att,
    unsigned short* __restrict__ fb,
    float* __restrict__ g,
    float* __restrict__ h)
{
    const int lane = threadIdx.x & 31;
    const int row  = blockIdx.x * 8 + (threadIdx.x >> 5);
    if (row >= N_NODES) return;

    const float4 a_ref = *(const float4*)&att[4 * lane];
    const float4 a_nei = *(const float4*)&att[D_FEAT + 4 * lane];
    const float4 f     = *(const float4*)&feat[(size_t)row * D_FEAT + 4 * lane];

    float sr = f.x * a_ref.x + f.y * a_ref.y + f.z * a_ref.z + f.w * a_ref.w;
    float sn = f.x * a_nei.x + f.y * a_nei.y + f.z * a_nei.z + f.w * a_nei.w;
    #pragma unroll
    for (int off = 16; off >= 1; off >>= 1) {
        sr += __shfl_xor(sr, off, 32);
        sn += __shfl_xor(sn, off, 32);
    }
    if (lane == 0) { h[row] = sr; g[row] = sn; }

    ushort4 u;
    u.x = f2bf(f.x); u.y = f2bf(f.y); u.z = f2bf(f.z); u.w = f2bf(f.w);
    *(ushort4*)&fb[(size_t)row * D_FEAT + 4 * lane] = u;
}

// ---------- Phase 2: weights from g/h, gather bf16 rows, weighted sum, ELU ----
__global__ __launch_bounds__(256, 8) void gather_kernel(
    const unsigned short* __restrict__ fb,
    const int*   __restrict__ nei,
    const float* __restrict__ g,
    const float* __restrict__ h,
    float*       __restrict__ out)
{
    const int lane = threadIdx.x & 31;
    const int node = blockIdx.x * 8 + (threadIdx.x >> 5);
    if (node >= N_NODES) return;

    // lane k owns neighbor k: weight computed fully in parallel, no per-k reduce
    const int   idx   = nei[node * K_NEI + lane];
    float score = h[node] + g[idx];
    score = (score >= 0.f) ? score : LEAKY * score;
    float p = __expf(score);              // no-max softmax: |score| <~ 15, f32-safe

    float denom = p;
    #pragma unroll
    for (int off = 16; off >= 1; off >>= 1)
        denom += __shfl_xor(denom, off, 32);
    const float w = p / denom;

    float4 o = {0.f, 0.f, 0.f, 0.f};
    #pragma unroll
    for (int k = 0; k < K_NEI; ++k) {
        const int   nk = __shfl(idx, k, 32);
        const float wk = __shfl(w,   k, 32);
        const ushort4 v = *(const ushort4*)&fb[(size_t)nk * D_FEAT + 4 * lane];
        o.x += wk * bf2f(v.x);
        o.y += wk * bf2f(v.y);
        o.z += wk * bf2f(v.z);
        o.w += wk * bf2f(v.w);
    }

    float4 r;
    r.x = (o.x > 0.f) ? o.x : expm1f(o.x);
    r.y = (o.y > 0.f) ? o.y : expm1f(o.y);
    r.z = (o.z > 0.f) ? o.z : expm1f(o.z);
    r.w = (o.w > 0.f) ? o.w : expm1f(o.w);
    *(float4*)&out[(size_t)node * D_FEAT + 4 * lane] = r;
}

// ---------- Fallback (round-1 kernel) if workspace too small ----------
__global__ __launch_bounds__(256, 4) void feat_encoder_fallback(
    const float* __restrict__ feat,
    const int*   __restrict__ nei,
    const float* __restrict__ att,
    float*       __restrict__ out)
{
    const int lane = threadIdx.x & 31;
    const int node = blockIdx.x * 8 + (threadIdx.x >> 5);
    if (node >= N_NODES) return;

    const float4 a_ref = *(const float4*)&att[4 * lane];
    const float4 a_nei = *(const float4*)&att[D_FEAT + 4 * lane];

    const float4 f = *(const float4*)&feat[(size_t)node * D_FEAT + 4 * lane];
    float sref = f.x * a_ref.x + f.y * a_ref.y + f.z * a_ref.z + f.w * a_ref.w;
    #pragma unroll
    for (int off = 16; off >= 1; off >>= 1)
        sref += __shfl_xor(sref, off, 32);

    const int idx = nei[node * K_NEI + lane];
    float  s = 0.f;
    float4 o = {0.f, 0.f, 0.f, 0.f};
    #pragma unroll
    for (int k = 0; k < K_NEI; ++k) {
        const int nk = __shfl(idx, k, 32);
        const float4 v = *(const float4*)&feat[(size_t)nk * D_FEAT + 4 * lane];
        float partial = v.x * a_nei.x + v.y * a_nei.y + v.z * a_nei.z + v.w * a_nei.w;
        #pragma unroll
        for (int off = 16; off >= 1; off >>= 1)
            partial += __shfl_xor(partial, off, 32);
        float score = partial + sref;
        score = (score >= 0.f) ? score : LEAKY * score;
        const float p = __expf(score);
        s += p;
        o.x += p * v.x; o.y += p * v.y; o.z += p * v.z; o.w += p * v.w;
    }
    const float inv = 1.0f / s;
    float4 r;
    r.x = o.x * inv; r.y = o.y * inv; r.z = o.z * inv; r.w = o.w * inv;
    r.x = (r.x > 0.f) ? r.x : expm1f(r.x);
    r.y = (r.y > 0.f) ? r.y : expm1f(r.y);
    r.z = (r.z > 0.f) ? r.z : expm1f(r.z);
    r.w = (r.w > 0.f) ? r.w : expm1f(r.w);
    *(float4*)&out[(size_t)node * D_FEAT + 4 * lane] = r;
}

extern "C" void kernel_launch(void* const* d_in, const int* in_sizes, int n_in,
                              void* d_out, int out_size, void* d_ws, size_t ws_size,
                              hipStream_t stream) {
    const float* feat = (const float*)d_in[0];
    const int*   nei  = (const int*)d_in[1];
    const float* att  = (const float*)d_in[2];
    float*       out  = (float*)d_out;

    const size_t fb_bytes = (size_t)N_NODES * D_FEAT * sizeof(unsigned short); // 12.8 MB
    const size_t g_bytes  = (size_t)N_NODES * sizeof(float);                   // 200 KB
    const size_t need     = fb_bytes + 2 * g_bytes;

    const dim3 grid((N_NODES + 7) / 8);

    if (ws_size >= need) {
        unsigned short* fb = (unsigned short*)d_ws;
        float* g = (float*)((char*)d_ws + fb_bytes);
        float* h = (float*)((char*)d_ws + fb_bytes + g_bytes);
        precompute_kernel<<<grid, 256, 0, stream>>>(feat, att, fb, g, h);
        gather_kernel<<<grid, 256, 0, stream>>>(fb, nei, g, h, out);
    } else {
        feat_encoder_fallback<<<grid, 256, 0, stream>>>(feat, nei, att, out);
    }
}

// Round 3
// 131.761 us; speedup vs baseline: 2.0209x; 1.6814x over previous
//
#include <hip/hip_runtime.h>
#include <hip/hip_bf16.h>
#include <math.h>

#define N_NODES 50000
#define K_NEI   32
#define D_FEAT  128
#define LEAKY   0.01f

#define NPG  7                         // nodes per 32-lane group
#define GPB  8                         // groups per 256-thread block
#define NPB  (NPG * GPB)               // 56 nodes per block
#define GRID ((N_NODES + NPB - 1) / NPB)   // 893 blocks <= 1024 co-resident @4/CU

#define CHUNK_SHIFT 12                 // 4096 rows = 2 MB bf16 per chunk
#define CHUNK_ROWS  (1 << CHUNK_SHIFT)
#define NCHUNKS     ((N_NODES + CHUNK_ROWS - 1) / CHUNK_ROWS)   // 13

__device__ __forceinline__ float bf2f(unsigned short u) {
    return __uint_as_float(((unsigned int)u) << 16);
}
__device__ __forceinline__ unsigned short f2bf(float x) {
    __hip_bfloat16 b = __float2bfloat16(x);   // RNE
    union { __hip_bfloat16 b; unsigned short u; } c; c.b = b;
    return c.u;
}

// ---------- Phase 1: g = feat.a_nei, h = feat.a_ref, fb = bf16(feat) ----------
__global__ __launch_bounds__(256) void precompute_kernel(
    const float* __restrict__ feat,
    const float* __restrict__ att,
    unsigned short* __restrict__ fb,
    float* __restrict__ g,
    float* __restrict__ h)
{
    const int lane = threadIdx.x & 31;
    const int row  = blockIdx.x * 8 + (threadIdx.x >> 5);
    if (row >= N_NODES) return;

    const float4 a_ref = *(const float4*)&att[4 * lane];
    const float4 a_nei = *(const float4*)&att[D_FEAT + 4 * lane];
    const float4 f     = *(const float4*)&feat[(size_t)row * D_FEAT + 4 * lane];

    float sr = f.x * a_ref.x + f.y * a_ref.y + f.z * a_ref.z + f.w * a_ref.w;
    float sn = f.x * a_nei.x + f.y * a_nei.y + f.z * a_nei.z + f.w * a_nei.w;
    #pragma unroll
    for (int off = 16; off >= 1; off >>= 1) {
        sr += __shfl_xor(sr, off, 32);
        sn += __shfl_xor(sn, off, 32);
    }
    if (lane == 0) { h[row] = sr; g[row] = sn; }

    ushort4 u;
    u.x = f2bf(f.x); u.y = f2bf(f.y); u.z = f2bf(f.z); u.w = f2bf(f.w);
    *(ushort4*)&fb[(size_t)row * D_FEAT + 4 * lane] = u;
}

// ---------- Phase 2: chunk-ordered gather for L2 residency ----------
__global__ __launch_bounds__(256, 4) void gather_chunked(
    const unsigned short* __restrict__ fb,
    const int*   __restrict__ nei,
    const float* __restrict__ g,
    const float* __restrict__ h,
    float*       __restrict__ out)
{
    const int lane       = threadIdx.x & 31;
    const int group      = blockIdx.x * GPB + (threadIdx.x >> 5);
    const int half_shift = threadIdx.x & 32;   // 0 for lower half-wave, 32 for upper
    const int node0      = group * NPG;

    int      idxA[NPG];
    float    wA[NPG];
    unsigned maskA[NPG];
    float4   oA[NPG];

    #pragma unroll
    for (int j = 0; j < NPG; ++j) {
        const int  node  = node0 + j;
        const bool valid = (node < N_NODES);

        const int idx = valid ? nei[node * K_NEI + lane] : 0;
        float sc = valid ? (h[node] + g[idx]) : 0.f;
        sc = (sc >= 0.f) ? sc : LEAKY * sc;
        const float p = __expf(sc);          // no-max softmax: |score| small, f32-safe
        float denom = p;
        #pragma unroll
        for (int off = 16; off >= 1; off >>= 1)
            denom += __shfl_xor(denom, off, 32);

        idxA[j] = idx;
        wA[j]   = p / denom;
        oA[j]   = make_float4(0.f, 0.f, 0.f, 0.f);
        maskA[j] = 0u;

        const int cid = idx >> CHUNK_SHIFT;
        #pragma unroll
        for (int c = 0; c < NCHUNKS; ++c) {
            const unsigned long long b = __ballot(valid && (cid == c));
            const unsigned m = (unsigned)(b >> half_shift);
            if (lane == c) maskA[j] = m;     // lane c archives chunk-c mask
        }
    }

    for (int c = 0; c < NCHUNKS; ++c) {
        #pragma unroll
        for (int j = 0; j < NPG; ++j) {
            unsigned m = (unsigned)__shfl((int)maskA[j], c, 32);
            while (m) {
                const int k = __ffs(m) - 1;
                m &= m - 1;
                const int   nk = __shfl(idxA[j], k, 32);
                const float wk = __shfl(wA[j],   k, 32);
                const ushort4 v = *(const ushort4*)&fb[(size_t)nk * D_FEAT + 4 * lane];
                oA[j].x += wk * bf2f(v.x);
                oA[j].y += wk * bf2f(v.y);
                oA[j].z += wk * bf2f(v.z);
                oA[j].w += wk * bf2f(v.w);
            }
        }
    }

    #pragma unroll
    for (int j = 0; j < NPG; ++j) {
        const int node = node0 + j;
        if (node < N_NODES) {
            float4 r;
            r.x = (oA[j].x > 0.f) ? oA[j].x : expm1f(oA[j].x);
            r.y = (oA[j].y > 0.f) ? oA[j].y : expm1f(oA[j].y);
            r.z = (oA[j].z > 0.f) ? oA[j].z : expm1f(oA[j].z);
            r.w = (oA[j].w > 0.f) ? oA[j].w : expm1f(oA[j].w);
            *(float4*)&out[(size_t)node * D_FEAT + 4 * lane] = r;
        }
    }
}

// ---------- Fallback (round-1 kernel) if workspace too small ----------
__global__ __launch_bounds__(256, 4) void feat_encoder_fallback(
    const float* __restrict__ feat,
    const int*   __restrict__ nei,
    const float* __restrict__ att,
    float*       __restrict__ out)
{
    const int lane = threadIdx.x & 31;
    const int node = blockIdx.x * 8 + (threadIdx.x >> 5);
    if (node >= N_NODES) return;

    const float4 a_ref = *(const float4*)&att[4 * lane];
    const float4 a_nei = *(const float4*)&att[D_FEAT + 4 * lane];

    const float4 f = *(const float4*)&feat[(size_t)node * D_FEAT + 4 * lane];
    float sref = f.x * a_ref.x + f.y * a_ref.y + f.z * a_ref.z + f.w * a_ref.w;
    #pragma unroll
    for (int off = 16; off >= 1; off >>= 1)
        sref += __shfl_xor(sref, off, 32);

    const int idx = nei[node * K_NEI + lane];
    float  s = 0.f;
    float4 o = {0.f, 0.f, 0.f, 0.f};
    #pragma unroll
    for (int k = 0; k < K_NEI; ++k) {
        const int nk = __shfl(idx, k, 32);
        const float4 v = *(const float4*)&feat[(size_t)nk * D_FEAT + 4 * lane];
        float partial = v.x * a_nei.x + v.y * a_nei.y + v.z * a_nei.z + v.w * a_nei.w;
        #pragma unroll
        for (int off = 16; off >= 1; off >>= 1)
            partial += __shfl_xor(partial, off, 32);
        float score = partial + sref;
        score = (score >= 0.f) ? score : LEAKY * score;
        const float p = __expf(score);
        s += p;
        o.x += p * v.x; o.y += p * v.y; o.z += p * v.z; o.w += p * v.w;
    }
    const float inv = 1.0f / s;
    float4 r;
    r.x = o.x * inv; r.y = o.y * inv; r.z = o.z * inv; r.w = o.w * inv;
    r.x = (r.x > 0.f) ? r.x : expm1f(r.x);
    r.y = (r.y > 0.f) ? r.y : expm1f(r.y);
    r.z = (r.z > 0.f) ? r.z : expm1f(r.z);
    r.w = (r.w > 0.f) ? r.w : expm1f(r.w);
    *(float4*)&out[(size_t)node * D_FEAT + 4 * lane] = r;
}

extern "C" void kernel_launch(void* const* d_in, const int* in_sizes, int n_in,
                              void* d_out, int out_size, void* d_ws, size_t ws_size,
                              hipStream_t stream) {
    const float* feat = (const float*)d_in[0];
    const int*   nei  = (const int*)d_in[1];
    const float* att  = (const float*)d_in[2];
    float*       out  = (float*)d_out;

    const size_t fb_bytes = (size_t)N_NODES * D_FEAT * sizeof(unsigned short); // 12.8 MB
    const size_t g_bytes  = (size_t)N_NODES * sizeof(float);                   // 200 KB
    const size_t need     = fb_bytes + 2 * g_bytes;

    if (ws_size >= need) {
        unsigned short* fb = (unsigned short*)d_ws;
        float* g = (float*)((char*)d_ws + fb_bytes);
        float* h = (float*)((char*)d_ws + fb_bytes + g_bytes);
        precompute_kernel<<<dim3((N_NODES + 7) / 8), 256, 0, stream>>>(feat, att, fb, g, h);
        gather_chunked<<<dim3(GRID), 256, 0, stream>>>(fb, nei, g, h, out);
    } else {
        feat_encoder_fallback<<<dim3((N_NODES + 7) / 8), 256, 0, stream>>>(feat, nei, att, out);
    }
}

// Round 4
// 92.936 us; speedup vs baseline: 2.8651x; 1.4178x over previous
//
#include <hip/hip_runtime.h>
#include <hip/hip_bf16.h>
#include <math.h>

#define N_NODES 50000
#define K_NEI   32
#define D_FEAT  128
#define LEAKY   0.01f

#define NPG  4                         // nodes per 32-lane group
#define GPB  8                         // groups per 256-thread block
#define NPB  (NPG * GPB)               // 32 nodes per block
#define GRID ((N_NODES + NPB - 1) / NPB)   // 1563 blocks, co-resident @8/CU

#define CHUNK_SHIFT 12                 // 4096 rows = 2 MB bf16 per chunk
#define CHUNK_ROWS  (1 << CHUNK_SHIFT)
#define NCHUNKS     ((N_NODES + CHUNK_ROWS - 1) / CHUNK_ROWS)   // 13

__device__ __forceinline__ float bf2f(unsigned short u) {
    return __uint_as_float(((unsigned int)u) << 16);
}
__device__ __forceinline__ unsigned short f2bf(float x) {
    __hip_bfloat16 b = __float2bfloat16(x);   // RNE
    union { __hip_bfloat16 b; unsigned short u; } c; c.b = b;
    return c.u;
}

// ---------- Phase 1: g = feat.a_nei, h = feat.a_ref, fb = bf16(feat) ----------
__global__ __launch_bounds__(256) void precompute_kernel(
    const float* __restrict__ feat,
    const float* __restrict__ att,
    unsigned short* __restrict__ fb,
    float* __restrict__ g,
    float* __restrict__ h)
{
    const int lane = threadIdx.x & 31;
    const int row  = blockIdx.x * 8 + (threadIdx.x >> 5);
    if (row >= N_NODES) return;

    const float4 a_ref = *(const float4*)&att[4 * lane];
    const float4 a_nei = *(const float4*)&att[D_FEAT + 4 * lane];
    const float4 f     = *(const float4*)&feat[(size_t)row * D_FEAT + 4 * lane];

    float sr = f.x * a_ref.x + f.y * a_ref.y + f.z * a_ref.z + f.w * a_ref.w;
    float sn = f.x * a_nei.x + f.y * a_nei.y + f.z * a_nei.z + f.w * a_nei.w;
    #pragma unroll
    for (int off = 16; off >= 1; off >>= 1) {
        sr += __shfl_xor(sr, off, 32);
        sn += __shfl_xor(sn, off, 32);
    }
    if (lane == 0) { h[row] = sr; g[row] = sn; }

    ushort4 u;
    u.x = f2bf(f.x); u.y = f2bf(f.y); u.z = f2bf(f.z); u.w = f2bf(f.w);
    *(ushort4*)&fb[(size_t)row * D_FEAT + 4 * lane] = u;
}

// ---------- Phase 2: chunk-ordered gather for L2 residency ----------
__global__ __launch_bounds__(256, 8) void gather_chunked(
    const unsigned short* __restrict__ fb,
    const int*   __restrict__ nei,
    const float* __restrict__ g,
    const float* __restrict__ h,
    float*       __restrict__ out)
{
    const int lane       = threadIdx.x & 31;
    const int group      = blockIdx.x * GPB + (threadIdx.x >> 5);
    const int half_shift = threadIdx.x & 32;   // 0 lower half-wave, 32 upper
    const int node0      = group * NPG;

    int      idxA[NPG];
    float    wA[NPG];
    unsigned maskA[NPG];
    float4   oA[NPG];

    #pragma unroll
    for (int j = 0; j < NPG; ++j) {
        const int  node  = node0 + j;
        const bool valid = (node < N_NODES);

        const int idx = valid ? nei[node * K_NEI + lane] : 0;
        float sc = valid ? (h[node] + g[idx]) : 0.f;
        sc = (sc >= 0.f) ? sc : LEAKY * sc;
        const float p = __expf(sc);          // no-max softmax: |score| small, f32-safe
        float denom = p;
        #pragma unroll
        for (int off = 16; off >= 1; off >>= 1)
            denom += __shfl_xor(denom, off, 32);

        idxA[j] = idx;
        wA[j]   = p / denom;
        oA[j]   = make_float4(0.f, 0.f, 0.f, 0.f);
        maskA[j] = 0u;

        const int cid = idx >> CHUNK_SHIFT;
        #pragma unroll
        for (int c = 0; c < NCHUNKS; ++c) {
            const unsigned long long b = __ballot(valid && (cid == c));
            const unsigned m = (unsigned)(b >> half_shift);
            if (lane == c) maskA[j] = m;     // lane c archives chunk-c mask
        }
    }

    for (int c = 0; c < NCHUNKS; ++c) {
        #pragma unroll
        for (int j = 0; j < NPG; ++j) {
            unsigned m = (unsigned)__shfl((int)maskA[j], c, 32);
            while (m) {
                const int k = __ffs(m) - 1;
                m &= m - 1;
                const int   nk = __shfl(idxA[j], k, 32);
                const float wk = __shfl(wA[j],   k, 32);
                const ushort4 v = *(const ushort4*)&fb[(size_t)nk * D_FEAT + 4 * lane];
                oA[j].x += wk * bf2f(v.x);
                oA[j].y += wk * bf2f(v.y);
                oA[j].z += wk * bf2f(v.z);
                oA[j].w += wk * bf2f(v.w);
            }
        }
    }

    #pragma unroll
    for (int j = 0; j < NPG; ++j) {
        const int node = node0 + j;
        if (node < N_NODES) {
            float4 r;
            r.x = (oA[j].x > 0.f) ? oA[j].x : expm1f(oA[j].x);
            r.y = (oA[j].y > 0.f) ? oA[j].y : expm1f(oA[j].y);
            r.z = (oA[j].z > 0.f) ? oA[j].z : expm1f(oA[j].z);
            r.w = (oA[j].w > 0.f) ? oA[j].w : expm1f(oA[j].w);
            *(float4*)&out[(size_t)node * D_FEAT + 4 * lane] = r;
        }
    }
}

// ---------- Fallback (round-1 kernel) if workspace too small ----------
__global__ __launch_bounds__(256, 4) void feat_encoder_fallback(
    const float* __restrict__ feat,
    const int*   __restrict__ nei,
    const float* __restrict__ att,
    float*       __restrict__ out)
{
    const int lane = threadIdx.x & 31;
    const int node = blockIdx.x * 8 + (threadIdx.x >> 5);
    if (node >= N_NODES) return;

    const float4 a_ref = *(const float4*)&att[4 * lane];
    const float4 a_nei = *(const float4*)&att[D_FEAT + 4 * lane];

    const float4 f = *(const float4*)&feat[(size_t)node * D_FEAT + 4 * lane];
    float sref = f.x * a_ref.x + f.y * a_ref.y + f.z * a_ref.z + f.w * a_ref.w;
    #pragma unroll
    for (int off = 16; off >= 1; off >>= 1)
        sref += __shfl_xor(sref, off, 32);

    const int idx = nei[node * K_NEI + lane];
    float  s = 0.f;
    float4 o = {0.f, 0.f, 0.f, 0.f};
    #pragma unroll
    for (int k = 0; k < K_NEI; ++k) {
        const int nk = __shfl(idx, k, 32);
        const float4 v = *(const float4*)&feat[(size_t)nk * D_FEAT + 4 * lane];
        float partial = v.x * a_nei.x + v.y * a_nei.y + v.z * a_nei.z + v.w * a_nei.w;
        #pragma unroll
        for (int off = 16; off >= 1; off >>= 1)
            partial += __shfl_xor(partial, off, 32);
        float score = partial + sref;
        score = (score >= 0.f) ? score : LEAKY * score;
        const float p = __expf(score);
        s += p;
        o.x += p * v.x; o.y += p * v.y; o.z += p * v.z; o.w += p * v.w;
    }
    const float inv = 1.0f / s;
    float4 r;
    r.x = o.x * inv; r.y = o.y * inv; r.z = o.z * inv; r.w = o.w * inv;
    r.x = (r.x > 0.f) ? r.x : expm1f(r.x);
    r.y = (r.y > 0.f) ? r.y : expm1f(r.y);
    r.z = (r.z > 0.f) ? r.z : expm1f(r.z);
    r.w = (r.w > 0.f) ? r.w : expm1f(r.w);
    *(float4*)&out[(size_t)node * D_FEAT + 4 * lane] = r;
}

extern "C" void kernel_launch(void* const* d_in, const int* in_sizes, int n_in,
                              void* d_out, int out_size, void* d_ws, size_t ws_size,
                              hipStream_t stream) {
    const float* feat = (const float*)d_in[0];
    const int*   nei  = (const int*)d_in[1];
    const float* att  = (const float*)d_in[2];
    float*       out  = (float*)d_out;

    const size_t fb_bytes = (size_t)N_NODES * D_FEAT * sizeof(unsigned short); // 12.8 MB
    const size_t g_bytes  = (size_t)N_NODES * sizeof(float);                   // 200 KB
    const size_t need     = fb_bytes + 2 * g_bytes;

    if (ws_size >= need) {
        unsigned short* fb = (unsigned short*)d_ws;
        float* g = (float*)((char*)d_ws + fb_bytes);
        float* h = (float*)((char*)d_ws + fb_bytes + g_bytes);
        precompute_kernel<<<dim3((N_NODES + 7) / 8), 256, 0, stream>>>(feat, att, fb, g, h);
        gather_chunked<<<dim3(GRID), 256, 0, stream>>>(fb, nei, g, h, out);
    } else {
        feat_encoder_fallback<<<dim3((N_NODES + 7) / 8), 256, 0, stream>>>(feat, nei, att, out);
    }
}